// Round 3
// baseline (414.421 us; speedup 1.0000x reference)
//
#include <hip/hip_runtime.h>

#define B_ 128
#define T_ 256
#define H_ 768
#define K_ 64
#define BT_ (B_ * T_)

// ---------------------------------------------------------------------------
// DPP helpers: wave-wide max in ~6 VALU ops (row_shr/bcast ladder).
// dpp_ctrl must be a compile-time constant -> template parameter.
// ---------------------------------------------------------------------------
template <int CTRL>
__device__ __forceinline__ float dpp_mov_f(float x) {
    return __int_as_float(__builtin_amdgcn_update_dpp(
        __float_as_int(x), __float_as_int(x), CTRL, 0xF, 0xF, false));
}
// max across all 64 lanes, returned uniform (via readlane 63)
__device__ __forceinline__ float wave_max64(float x) {
    x = fmaxf(x, dpp_mov_f<0x111>(x));  // row_shr:1
    x = fmaxf(x, dpp_mov_f<0x112>(x));  // row_shr:2
    x = fmaxf(x, dpp_mov_f<0x114>(x));  // row_shr:4
    x = fmaxf(x, dpp_mov_f<0x118>(x));  // row_shr:8
    x = fmaxf(x, dpp_mov_f<0x142>(x));  // row_bcast:15
    x = fmaxf(x, dpp_mov_f<0x143>(x));  // row_bcast:31
    return __int_as_float(__builtin_amdgcn_readlane(__float_as_int(x), 63));
}
__device__ __forceinline__ float readlane0_f(float x) {
    return __int_as_float(__builtin_amdgcn_readfirstlane(__float_as_int(x)));
}

// ---------------------------------------------------------------------------
// Kernel A: emissions[bt][k] = hidden[bt][:] @ W[:][k] + b[k]   (fp32)
// 512 blocks x 256 threads; block = 64 rows; wave = 16 rows; lane = class k.
// A staged in LDS, read as same-address-broadcast b128 (conflict-free).
// W chunk (64 h-values for column k=lane) held in 64 VGPRs.
// ---------------------------------------------------------------------------
__global__ __launch_bounds__(256, 2) void gemm_emis(const float* __restrict__ hidden,
                                                    const float* __restrict__ W,
                                                    const float* __restrict__ bias,
                                                    float* __restrict__ emis) {
    __shared__ __align__(16) float At[64 * 64];

    const int tid = threadIdx.x;
    const int lane = tid & 63;
    const int wv = tid >> 6;            // 0..3
    const int rowbase = blockIdx.x * 64;
    const int r0 = wv * 16;

    float acc[16];
    const float bb = bias[lane];
#pragma unroll
    for (int r = 0; r < 16; ++r) acc[r] = bb;

    for (int hb = 0; hb < H_; hb += 64) {
        // stage A tile: 64 rows x 64 h, coalesced float4
#pragma unroll
        for (int k = 0; k < 4; ++k) {
            int flat = tid + k * 256;
            int row = flat >> 4;
            int h4 = flat & 15;
            *(float4*)&At[row * 64 + h4 * 4] =
                *(const float4*)&hidden[(size_t)(rowbase + row) * H_ + hb + h4 * 4];
        }
        // W chunk for this lane's column into registers (coalesced across lanes)
        float Wr[64];
#pragma unroll
        for (int h = 0; h < 64; ++h) Wr[h] = W[(size_t)(hb + h) * K_ + lane];
        __syncthreads();

#pragma unroll
        for (int rg = 0; rg < 4; ++rg) {
#pragma unroll
            for (int h4 = 0; h4 < 16; ++h4) {
                float4 a0 = *(const float4*)&At[(r0 + rg * 4 + 0) * 64 + h4 * 4];
                float4 a1 = *(const float4*)&At[(r0 + rg * 4 + 1) * 64 + h4 * 4];
                float4 a2 = *(const float4*)&At[(r0 + rg * 4 + 2) * 64 + h4 * 4];
                float4 a3 = *(const float4*)&At[(r0 + rg * 4 + 3) * 64 + h4 * 4];
                float w0 = Wr[h4 * 4 + 0], w1 = Wr[h4 * 4 + 1];
                float w2 = Wr[h4 * 4 + 2], w3 = Wr[h4 * 4 + 3];
                acc[rg * 4 + 0] += a0.x * w0; acc[rg * 4 + 0] += a0.y * w1;
                acc[rg * 4 + 0] += a0.z * w2; acc[rg * 4 + 0] += a0.w * w3;
                acc[rg * 4 + 1] += a1.x * w0; acc[rg * 4 + 1] += a1.y * w1;
                acc[rg * 4 + 1] += a1.z * w2; acc[rg * 4 + 1] += a1.w * w3;
                acc[rg * 4 + 2] += a2.x * w0; acc[rg * 4 + 2] += a2.y * w1;
                acc[rg * 4 + 2] += a2.z * w2; acc[rg * 4 + 2] += a2.w * w3;
                acc[rg * 4 + 3] += a3.x * w0; acc[rg * 4 + 3] += a3.y * w1;
                acc[rg * 4 + 3] += a3.z * w2; acc[rg * 4 + 3] += a3.w * w3;
            }
        }
        __syncthreads();
    }
#pragma unroll
    for (int r = 0; r < 16; ++r)
        emis[(size_t)(rowbase + r0 + r) * K_ + lane] = acc[r];
}

// ---------------------------------------------------------------------------
// Kernel B: CRF. One wave (64 lanes = 64 states) per batch per recurrence.
// blocks 0..127  : forward log-norm (scaled-linear) + seq score -> out[32768+b]
// blocks 128..255: Viterbi value-only forward + recompute-backtrack -> path
// ---------------------------------------------------------------------------
__global__ __launch_bounds__(64, 1) void crf_kernel(const float* __restrict__ emis,
                                                    const int* __restrict__ masks,
                                                    const int* __restrict__ target,
                                                    const float* __restrict__ trans,
                                                    float* __restrict__ out) {
    __shared__ __align__(16) float vbuf[T_ * K_];   // 64 KB: v history / fwd r-buffer
    __shared__ float tbuf[K_ * 65];                 // trans rows, +1 pad (backtrack)

    const int lane = threadIdx.x;
    const int bid = blockIdx.x;
    const int b = (bid < B_) ? bid : bid - B_;

    int sl = 0;
#pragma unroll
    for (int k = 0; k < 4; ++k) sl += masks[b * T_ + lane + k * 64];
#pragma unroll
    for (int m = 32; m; m >>= 1) sl += __shfl_xor(sl, m, 64);
    const int seq_len = sl;

    const float* eb = emis + (size_t)b * (T_ * K_);

    if (bid < B_) {
        // ------------- forward log-norm, scaled-linear recurrence -------------
        // alpha_t = c_t + log(r_t);  r'_j = (Sum_i r_i E_ij) * exp(e_tj-e_t0) / S0
        // c' = c + e_t0 + log(S0).  exp/log/shfl all off the serial chain.
        float Ecol[64];
#pragma unroll
        for (int i = 0; i < 64; ++i) Ecol[i] = __expf(trans[i * K_ + lane]);

        float e0 = eb[lane];
        float a00 = readlane0_f(e0);
        float r = __expf(e0 - a00);
        float c = a00;

        float e_cur = eb[K_ + lane];
        float e0_cur = readlane0_f(e_cur);
        float x_cur = __expf(e_cur - e0_cur);

        for (int t = 1; t < T_; ++t) {
            float e_nxt = (t < T_ - 1) ? eb[(t + 1) * K_ + lane] : 0.f;
            vbuf[lane] = r;  // single wave: DS pipe in-order, no barrier
            float s0 = 0.f, s1 = 0.f, s2 = 0.f, s3 = 0.f;
#pragma unroll
            for (int i = 0; i < 16; ++i) {
                float4 p4 = *(const float4*)&vbuf[i * 4];
                s0 += p4.x * Ecol[i * 4 + 0];
                s1 += p4.y * Ecol[i * 4 + 1];
                s2 += p4.z * Ecol[i * 4 + 2];
                s3 += p4.w * Ecol[i * 4 + 3];
            }
            float S = (s0 + s1) + (s2 + s3);
            float S0 = readlane0_f(S);
            if (t < seq_len) {
                r = __fdividef(S * x_cur, S0);
                c += __logf(S0) + e0_cur;   // off critical chain
            }
            e_cur = e_nxt;
            e0_cur = readlane0_f(e_cur);
            x_cur = __expf(e_cur - e0_cur); // off critical chain
        }
        // log_norm = c + log(sum_j r_j)
        float rs = r;
#pragma unroll
        for (int m = 32; m; m >>= 1) rs += __shfl_xor(rs, m, 64);
        float log_norm = c + __logf(rs);

        // ---------------- sequence score ----------------
        float sc = 0.f;
#pragma unroll
        for (int k = 0; k < 4; ++k) {
            int t = lane + k * 64;
            if (t < seq_len) {
                int tg = target[b * T_ + t];
                sc += eb[t * K_ + tg];
                if (t >= 1) sc += trans[target[b * T_ + t - 1] * K_ + tg];
            }
        }
#pragma unroll
        for (int m = 32; m; m >>= 1) sc += __shfl_xor(sc, m, 64);
        if (lane == 0) out[BT_ + b] = sc - log_norm;
    } else {
        // ------------- Viterbi: value-only forward, recompute backtrack -------
        float Tcol[64];
#pragma unroll
        for (int i = 0; i < 64; ++i) Tcol[i] = trans[i * K_ + lane];
        // stage padded trans rows for backtrack: tbuf[i][j], stride 65
        for (int idx = lane; idx < K_ * K_; idx += 64)
            tbuf[(idx >> 6) * 65 + (idx & 63)] = trans[idx];

        float v = eb[lane];
        vbuf[lane] = v;
        float e_cur = eb[K_ + lane];
        for (int t = 1; t < T_; ++t) {
            float e_nxt = (t < T_ - 1) ? eb[(t + 1) * K_ + lane] : 0.f;
            const float* vp = &vbuf[(t - 1) * K_];
            float mm[4];
            mm[0] = mm[1] = mm[2] = mm[3] = -3.4e38f;
#pragma unroll
            for (int i = 0; i < 16; ++i) {
                float4 v4 = *(const float4*)&vp[i * 4];
                float q = fmaxf(fmaxf(v4.x + Tcol[i * 4 + 0], v4.y + Tcol[i * 4 + 1]),
                                fmaxf(v4.z + Tcol[i * 4 + 2], v4.w + Tcol[i * 4 + 3]));
                mm[i & 3] = fmaxf(mm[i & 3], q);
            }
            float M = fmaxf(fmaxf(mm[0], mm[1]), fmaxf(mm[2], mm[3]));
            if (t < seq_len) v = M + e_cur;
            vbuf[t * K_ + lane] = v;
            e_cur = e_nxt;
        }

        // last tag: first index of max over lanes (np.argmax tie rule)
        float M = wave_max64(v);
        unsigned long long ball = __ballot(v >= M);
        int tag = (int)__builtin_ctzll(ball);

        // backtrack: path kept in registers, tag recomputed exactly
        int path[4];
#pragma unroll
        for (int k = 0; k < 4; ++k) path[k] = 0;
        if (lane == ((T_ - 1) & 63)) path[(T_ - 1) >> 6] = tag;

        float vpre = vbuf[(T_ - 2) * K_ + lane];  // v_{t-1} for t = T-1
        for (int t = T_ - 1; t >= 1; --t) {
            float vnext = (t >= 2) ? vbuf[(t - 2) * K_ + lane] : 0.f;
            if (t < seq_len) {
                // argmax_i (v_{t-1}[i] + trans[i][tag]) — identical fp32 adds
                float s = vpre + tbuf[lane * 65 + tag];
                float Ms = wave_max64(s);
                unsigned long long bl = __ballot(s >= Ms);
                tag = (int)__builtin_ctzll(bl);
            }
            int p = t - 1;
            if (lane == (p & 63)) path[p >> 6] = tag;
            vpre = vnext;
        }
#pragma unroll
        for (int k = 0; k < 4; ++k) {
            int t = lane + k * 64;
            out[b * T_ + t] = (t < seq_len) ? (float)path[k] : 0.f;
        }
    }
}

// ---------------------------------------------------------------------------
extern "C" void kernel_launch(void* const* d_in, const int* in_sizes, int n_in,
                              void* d_out, int out_size, void* d_ws, size_t ws_size,
                              hipStream_t stream) {
    const float* hidden = (const float*)d_in[0];   // [B,T,H] fp32
    const int* masks    = (const int*)d_in[1];     // [B,T] int32
    const int* target   = (const int*)d_in[2];     // [B,T] int32
    const float* W      = (const float*)d_in[3];   // [H,K] fp32
    const float* bias   = (const float*)d_in[4];   // [K] fp32
    const float* trans  = (const float*)d_in[5];   // [K,K] fp32
    float* out = (float*)d_out;                    // [B*T] path + [B] ll, fp32
    float* emis = (float*)d_ws;                    // [B*T, K] fp32 scratch

    gemm_emis<<<dim3(BT_ / 64), dim3(256), 0, stream>>>(hidden, W, bias, emis);
    crf_kernel<<<dim3(2 * B_), dim3(64), 0, stream>>>(emis, masks, target, trans, out);
}

// Round 4
// 390.789 us; speedup vs baseline: 1.0605x; 1.0605x over previous
//
#include <hip/hip_runtime.h>

#define B_ 128
#define T_ 256
#define H_ 768
#define K_ 64
#define BT_ (B_ * T_)

// ---------------------------------------------------------------------------
// DPP helpers: wave-wide max in ~6 VALU ops (row_shr/bcast ladder).
// ---------------------------------------------------------------------------
template <int CTRL>
__device__ __forceinline__ float dpp_mov_f(float x) {
    return __int_as_float(__builtin_amdgcn_update_dpp(
        __float_as_int(x), __float_as_int(x), CTRL, 0xF, 0xF, false));
}
__device__ __forceinline__ float wave_max64(float x) {
    x = fmaxf(x, dpp_mov_f<0x111>(x));  // row_shr:1
    x = fmaxf(x, dpp_mov_f<0x112>(x));  // row_shr:2
    x = fmaxf(x, dpp_mov_f<0x114>(x));  // row_shr:4
    x = fmaxf(x, dpp_mov_f<0x118>(x));  // row_shr:8
    x = fmaxf(x, dpp_mov_f<0x142>(x));  // row_bcast:15
    x = fmaxf(x, dpp_mov_f<0x143>(x));  // row_bcast:31
    return __int_as_float(__builtin_amdgcn_readlane(__float_as_int(x), 63));
}
__device__ __forceinline__ float readlane0_f(float x) {
    return __int_as_float(__builtin_amdgcn_readfirstlane(__float_as_int(x)));
}

// ---------------------------------------------------------------------------
// Kernel A: emissions = hidden @ W + b   (fp32, M=32768, N=64, K=768)
// 256 blocks x 256 thr; block = 128 rows x 64 cols; wave = 16 cols;
// lane = 2 rows. A transposed in LDS (unique-byte b64 reads on DS pipe);
// W broadcast from global/L2 on the VMEM pipe. FMA-issue-bound by design.
// ---------------------------------------------------------------------------
#define BK_ 32
#define P_ 130   // padded row-stride of At: b64 reads aligned + 2-way max
__global__ __launch_bounds__(256) void gemm_emis(const float* __restrict__ hidden,
                                                 const float* __restrict__ W,
                                                 const float* __restrict__ bias,
                                                 float* __restrict__ emis) {
    __shared__ float At[BK_ * P_];   // [h][row], row-stride P_

    const int tid = threadIdx.x;
    const int lane = tid & 63;
    const int wc = __builtin_amdgcn_readfirstlane((tid >> 6) * 16);  // wave col base
    const int rowbase = blockIdx.x * 128;

    // staging assignment: float4 f = tid + i*256; row = f>>3 (8 f4/row), h4 = f&7
    const int srow = tid >> 3;        // 0..31  (+32 per i)
    const int sh4 = tid & 7;          // 0..7

    float acc0[16], acc1[16];
#pragma unroll
    for (int c = 0; c < 16; ++c) { acc0[c] = bias[wc + c]; acc1[c] = acc0[c]; }

    // prefetch k-block 0
    float4 pf[4];
#pragma unroll
    for (int i = 0; i < 4; ++i)
        pf[i] = *(const float4*)&hidden[(rowbase + srow + i * 32) * H_ + sh4 * 4];

    for (int kb = 0; kb < H_ / BK_; ++kb) {
        __syncthreads();  // previous inner-loop reads done
#pragma unroll
        for (int i = 0; i < 4; ++i) {
            int row = srow + i * 32;
            At[(sh4 * 4 + 0) * P_ + row] = pf[i].x;
            At[(sh4 * 4 + 1) * P_ + row] = pf[i].y;
            At[(sh4 * 4 + 2) * P_ + row] = pf[i].z;
            At[(sh4 * 4 + 3) * P_ + row] = pf[i].w;
        }
        __syncthreads();
        if (kb + 1 < H_ / BK_) {
#pragma unroll
            for (int i = 0; i < 4; ++i)
                pf[i] = *(const float4*)&hidden[(rowbase + srow + i * 32) * H_ +
                                                (kb + 1) * BK_ + sh4 * 4];
        }
        const float* Wk = &W[(kb * BK_) * K_ + wc];
#pragma unroll 8
        for (int h = 0; h < BK_; ++h) {
            float2 a = *(const float2*)&At[h * P_ + 2 * lane];
            float4 w0 = *(const float4*)&Wk[h * K_ + 0];
            float4 w1 = *(const float4*)&Wk[h * K_ + 4];
            float4 w2 = *(const float4*)&Wk[h * K_ + 8];
            float4 w3 = *(const float4*)&Wk[h * K_ + 12];
            acc0[0]  += a.x * w0.x; acc1[0]  += a.y * w0.x;
            acc0[1]  += a.x * w0.y; acc1[1]  += a.y * w0.y;
            acc0[2]  += a.x * w0.z; acc1[2]  += a.y * w0.z;
            acc0[3]  += a.x * w0.w; acc1[3]  += a.y * w0.w;
            acc0[4]  += a.x * w1.x; acc1[4]  += a.y * w1.x;
            acc0[5]  += a.x * w1.y; acc1[5]  += a.y * w1.y;
            acc0[6]  += a.x * w1.z; acc1[6]  += a.y * w1.z;
            acc0[7]  += a.x * w1.w; acc1[7]  += a.y * w1.w;
            acc0[8]  += a.x * w2.x; acc1[8]  += a.y * w2.x;
            acc0[9]  += a.x * w2.y; acc1[9]  += a.y * w2.y;
            acc0[10] += a.x * w2.z; acc1[10] += a.y * w2.z;
            acc0[11] += a.x * w2.w; acc1[11] += a.y * w2.w;
            acc0[12] += a.x * w3.x; acc1[12] += a.y * w3.x;
            acc0[13] += a.x * w3.y; acc1[13] += a.y * w3.y;
            acc0[14] += a.x * w3.z; acc1[14] += a.y * w3.z;
            acc0[15] += a.x * w3.w; acc1[15] += a.y * w3.w;
        }
    }

    float* e0 = &emis[(size_t)(rowbase + 2 * lane) * K_ + wc];
    float* e1 = &emis[(size_t)(rowbase + 2 * lane + 1) * K_ + wc];
#pragma unroll
    for (int q = 0; q < 4; ++q) {
        *(float4*)&e0[q * 4] = make_float4(acc0[q * 4], acc0[q * 4 + 1],
                                           acc0[q * 4 + 2], acc0[q * 4 + 3]);
        *(float4*)&e1[q * 4] = make_float4(acc1[q * 4], acc1[q * 4 + 1],
                                           acc1[q * 4 + 2], acc1[q * 4 + 3]);
    }
}

// ---------------------------------------------------------------------------
// Kernel B: CRF (unchanged from round 3 — passed with absmax 0).
// ---------------------------------------------------------------------------
__global__ __launch_bounds__(64, 1) void crf_kernel(const float* __restrict__ emis,
                                                    const int* __restrict__ masks,
                                                    const int* __restrict__ target,
                                                    const float* __restrict__ trans,
                                                    float* __restrict__ out) {
    __shared__ __align__(16) float vbuf[T_ * K_];
    __shared__ float tbuf[K_ * 65];

    const int lane = threadIdx.x;
    const int bid = blockIdx.x;
    const int b = (bid < B_) ? bid : bid - B_;

    int sl = 0;
#pragma unroll
    for (int k = 0; k < 4; ++k) sl += masks[b * T_ + lane + k * 64];
#pragma unroll
    for (int m = 32; m; m >>= 1) sl += __shfl_xor(sl, m, 64);
    const int seq_len = sl;

    const float* eb = emis + (size_t)b * (T_ * K_);

    if (bid < B_) {
        float Ecol[64];
#pragma unroll
        for (int i = 0; i < 64; ++i) Ecol[i] = __expf(trans[i * K_ + lane]);

        float e0 = eb[lane];
        float a00 = readlane0_f(e0);
        float r = __expf(e0 - a00);
        float c = a00;

        float e_cur = eb[K_ + lane];
        float e0_cur = readlane0_f(e_cur);
        float x_cur = __expf(e_cur - e0_cur);

        for (int t = 1; t < T_; ++t) {
            float e_nxt = (t < T_ - 1) ? eb[(t + 1) * K_ + lane] : 0.f;
            vbuf[lane] = r;
            float s0 = 0.f, s1 = 0.f, s2 = 0.f, s3 = 0.f;
#pragma unroll
            for (int i = 0; i < 16; ++i) {
                float4 p4 = *(const float4*)&vbuf[i * 4];
                s0 += p4.x * Ecol[i * 4 + 0];
                s1 += p4.y * Ecol[i * 4 + 1];
                s2 += p4.z * Ecol[i * 4 + 2];
                s3 += p4.w * Ecol[i * 4 + 3];
            }
            float S = (s0 + s1) + (s2 + s3);
            float S0 = readlane0_f(S);
            if (t < seq_len) {
                r = __fdividef(S * x_cur, S0);
                c += __logf(S0) + e0_cur;
            }
            e_cur = e_nxt;
            e0_cur = readlane0_f(e_cur);
            x_cur = __expf(e_cur - e0_cur);
        }
        float rs = r;
#pragma unroll
        for (int m = 32; m; m >>= 1) rs += __shfl_xor(rs, m, 64);
        float log_norm = c + __logf(rs);

        float sc = 0.f;
#pragma unroll
        for (int k = 0; k < 4; ++k) {
            int t = lane + k * 64;
            if (t < seq_len) {
                int tg = target[b * T_ + t];
                sc += eb[t * K_ + tg];
                if (t >= 1) sc += trans[target[b * T_ + t - 1] * K_ + tg];
            }
        }
#pragma unroll
        for (int m = 32; m; m >>= 1) sc += __shfl_xor(sc, m, 64);
        if (lane == 0) out[BT_ + b] = sc - log_norm;
    } else {
        float Tcol[64];
#pragma unroll
        for (int i = 0; i < 64; ++i) Tcol[i] = trans[i * K_ + lane];
        for (int idx = lane; idx < K_ * K_; idx += 64)
            tbuf[(idx >> 6) * 65 + (idx & 63)] = trans[idx];

        float v = eb[lane];
        vbuf[lane] = v;
        float e_cur = eb[K_ + lane];
        for (int t = 1; t < T_; ++t) {
            float e_nxt = (t < T_ - 1) ? eb[(t + 1) * K_ + lane] : 0.f;
            const float* vp = &vbuf[(t - 1) * K_];
            float mm[4];
            mm[0] = mm[1] = mm[2] = mm[3] = -3.4e38f;
#pragma unroll
            for (int i = 0; i < 16; ++i) {
                float4 v4 = *(const float4*)&vp[i * 4];
                float q = fmaxf(fmaxf(v4.x + Tcol[i * 4 + 0], v4.y + Tcol[i * 4 + 1]),
                                fmaxf(v4.z + Tcol[i * 4 + 2], v4.w + Tcol[i * 4 + 3]));
                mm[i & 3] = fmaxf(mm[i & 3], q);
            }
            float M = fmaxf(fmaxf(mm[0], mm[1]), fmaxf(mm[2], mm[3]));
            if (t < seq_len) v = M + e_cur;
            vbuf[t * K_ + lane] = v;
            e_cur = e_nxt;
        }

        float M = wave_max64(v);
        unsigned long long ball = __ballot(v >= M);
        int tag = (int)__builtin_ctzll(ball);

        int path[4];
#pragma unroll
        for (int k = 0; k < 4; ++k) path[k] = 0;
        if (lane == ((T_ - 1) & 63)) path[(T_ - 1) >> 6] = tag;

        float vpre = vbuf[(T_ - 2) * K_ + lane];
        for (int t = T_ - 1; t >= 1; --t) {
            float vnext = (t >= 2) ? vbuf[(t - 2) * K_ + lane] : 0.f;
            if (t < seq_len) {
                float s = vpre + tbuf[lane * 65 + tag];
                float Ms = wave_max64(s);
                unsigned long long bl = __ballot(s >= Ms);
                tag = (int)__builtin_ctzll(bl);
            }
            int p = t - 1;
            if (lane == (p & 63)) path[p >> 6] = tag;
            vpre = vnext;
        }
#pragma unroll
        for (int k = 0; k < 4; ++k) {
            int t = lane + k * 64;
            out[b * T_ + t] = (t < seq_len) ? (float)path[k] : 0.f;
        }
    }
}

// ---------------------------------------------------------------------------
extern "C" void kernel_launch(void* const* d_in, const int* in_sizes, int n_in,
                              void* d_out, int out_size, void* d_ws, size_t ws_size,
                              hipStream_t stream) {
    const float* hidden = (const float*)d_in[0];
    const int* masks    = (const int*)d_in[1];
    const int* target   = (const int*)d_in[2];
    const float* W      = (const float*)d_in[3];
    const float* bias   = (const float*)d_in[4];
    const float* trans  = (const float*)d_in[5];
    float* out = (float*)d_out;
    float* emis = (float*)d_ws;

    gemm_emis<<<dim3(BT_ / 128), dim3(256), 0, stream>>>(hidden, W, bias, emis);
    crf_kernel<<<dim3(2 * B_), dim3(64), 0, stream>>>(emis, masks, target, trans, out);
}

// Round 5
// 387.484 us; speedup vs baseline: 1.0695x; 1.0085x over previous
//
#include <hip/hip_runtime.h>

#define B_ 128
#define T_ 256
#define H_ 768
#define K_ 64
#define BT_ (B_ * T_)

// ---------------------------------------------------------------------------
// DPP helpers: wave-wide max in ~6 VALU ops (row_shr/bcast ladder).
// ---------------------------------------------------------------------------
template <int CTRL>
__device__ __forceinline__ float dpp_mov_f(float x) {
    return __int_as_float(__builtin_amdgcn_update_dpp(
        __float_as_int(x), __float_as_int(x), CTRL, 0xF, 0xF, false));
}
__device__ __forceinline__ float wave_max64(float x) {
    x = fmaxf(x, dpp_mov_f<0x111>(x));  // row_shr:1
    x = fmaxf(x, dpp_mov_f<0x112>(x));  // row_shr:2
    x = fmaxf(x, dpp_mov_f<0x114>(x));  // row_shr:4
    x = fmaxf(x, dpp_mov_f<0x118>(x));  // row_shr:8
    x = fmaxf(x, dpp_mov_f<0x142>(x));  // row_bcast:15
    x = fmaxf(x, dpp_mov_f<0x143>(x));  // row_bcast:31
    return __int_as_float(__builtin_amdgcn_readlane(__float_as_int(x), 63));
}
__device__ __forceinline__ float readlane0_f(float x) {
    return __int_as_float(__builtin_amdgcn_readfirstlane(__float_as_int(x)));
}

// ---------------------------------------------------------------------------
// Kernel A: emissions = hidden @ W + b  (unchanged from round 4)
// ---------------------------------------------------------------------------
#define BK_ 32
#define P_ 130
__global__ __launch_bounds__(256) void gemm_emis(const float* __restrict__ hidden,
                                                 const float* __restrict__ W,
                                                 const float* __restrict__ bias,
                                                 float* __restrict__ emis) {
    __shared__ float At[BK_ * P_];

    const int tid = threadIdx.x;
    const int lane = tid & 63;
    const int wc = __builtin_amdgcn_readfirstlane((tid >> 6) * 16);
    const int rowbase = blockIdx.x * 128;
    const int srow = tid >> 3;
    const int sh4 = tid & 7;

    float acc0[16], acc1[16];
#pragma unroll
    for (int c = 0; c < 16; ++c) { acc0[c] = bias[wc + c]; acc1[c] = acc0[c]; }

    float4 pf[4];
#pragma unroll
    for (int i = 0; i < 4; ++i)
        pf[i] = *(const float4*)&hidden[(rowbase + srow + i * 32) * H_ + sh4 * 4];

    for (int kb = 0; kb < H_ / BK_; ++kb) {
        __syncthreads();
#pragma unroll
        for (int i = 0; i < 4; ++i) {
            int row = srow + i * 32;
            At[(sh4 * 4 + 0) * P_ + row] = pf[i].x;
            At[(sh4 * 4 + 1) * P_ + row] = pf[i].y;
            At[(sh4 * 4 + 2) * P_ + row] = pf[i].z;
            At[(sh4 * 4 + 3) * P_ + row] = pf[i].w;
        }
        __syncthreads();
        if (kb + 1 < H_ / BK_) {
#pragma unroll
            for (int i = 0; i < 4; ++i)
                pf[i] = *(const float4*)&hidden[(rowbase + srow + i * 32) * H_ +
                                                (kb + 1) * BK_ + sh4 * 4];
        }
        const float* Wk = &W[(kb * BK_) * K_ + wc];
#pragma unroll 8
        for (int h = 0; h < BK_; ++h) {
            float2 a = *(const float2*)&At[h * P_ + 2 * lane];
            float4 w0 = *(const float4*)&Wk[h * K_ + 0];
            float4 w1 = *(const float4*)&Wk[h * K_ + 4];
            float4 w2 = *(const float4*)&Wk[h * K_ + 8];
            float4 w3 = *(const float4*)&Wk[h * K_ + 12];
            acc0[0]  += a.x * w0.x; acc1[0]  += a.y * w0.x;
            acc0[1]  += a.x * w0.y; acc1[1]  += a.y * w0.y;
            acc0[2]  += a.x * w0.z; acc1[2]  += a.y * w0.z;
            acc0[3]  += a.x * w0.w; acc1[3]  += a.y * w0.w;
            acc0[4]  += a.x * w1.x; acc1[4]  += a.y * w1.x;
            acc0[5]  += a.x * w1.y; acc1[5]  += a.y * w1.y;
            acc0[6]  += a.x * w1.z; acc1[6]  += a.y * w1.z;
            acc0[7]  += a.x * w1.w; acc1[7]  += a.y * w1.w;
            acc0[8]  += a.x * w2.x; acc1[8]  += a.y * w2.x;
            acc0[9]  += a.x * w2.y; acc1[9]  += a.y * w2.y;
            acc0[10] += a.x * w2.z; acc1[10] += a.y * w2.z;
            acc0[11] += a.x * w2.w; acc1[11] += a.y * w2.w;
            acc0[12] += a.x * w3.x; acc1[12] += a.y * w3.x;
            acc0[13] += a.x * w3.y; acc1[13] += a.y * w3.y;
            acc0[14] += a.x * w3.z; acc1[14] += a.y * w3.z;
            acc0[15] += a.x * w3.w; acc1[15] += a.y * w3.w;
        }
    }

    float* e0 = &emis[(size_t)(rowbase + 2 * lane) * K_ + wc];
    float* e1 = &emis[(size_t)(rowbase + 2 * lane + 1) * K_ + wc];
#pragma unroll
    for (int q = 0; q < 4; ++q) {
        *(float4*)&e0[q * 4] = make_float4(acc0[q * 4], acc0[q * 4 + 1],
                                           acc0[q * 4 + 2], acc0[q * 4 + 3]);
        *(float4*)&e1[q * 4] = make_float4(acc1[q * 4], acc1[q * 4 + 1],
                                           acc1[q * 4 + 2], acc1[q * 4 + 3]);
    }
}

// ---------------------------------------------------------------------------
// Kernel B: fused CRF. 128 blocks x 128 thr (2 waves): wave0 = forward
// log-norm + seq score; wave1 = Viterbi + backtrack. Emissions staged to
// LDS once. Forward uses delayed normalization: per-step serial chain is
// write -> 16 batched ds_read_b128 -> 8-chain FMA dot -> 1 mul -> write.
// ---------------------------------------------------------------------------
__global__ __launch_bounds__(128, 1) void crf_kernel(const float* __restrict__ emis,
                                                     const int* __restrict__ masks,
                                                     const int* __restrict__ target,
                                                     const float* __restrict__ trans,
                                                     float* __restrict__ out) {
    __shared__ __align__(16) float ebuf[T_ * K_];   // 64 KB emissions for batch b
    __shared__ __align__(16) float vbuf[T_ * K_];   // 64 KB viterbi v-history
    __shared__ float tbuf[K_ * 65];                 // padded trans rows (backtrack)
    __shared__ __align__(16) float pbuf[64];        // forward p broadcast

    const int tid = threadIdx.x;
    const int lane = tid & 63;
    const int b = blockIdx.x;
    const float* eb = emis + (size_t)b * (T_ * K_);

    // stage emissions: 4096 float4s over 128 threads
    {
        const float4* src = (const float4*)eb;
        float4* dst = (float4*)ebuf;
#pragma unroll
        for (int k = 0; k < 32; ++k) dst[tid + k * 128] = src[tid + k * 128];
    }
    int sl = 0;
#pragma unroll
    for (int k = 0; k < 4; ++k) sl += masks[b * T_ + lane + k * 64];
#pragma unroll
    for (int m = 32; m; m >>= 1) sl += __shfl_xor(sl, m, 64);
    const int seq_len = sl;
    __syncthreads();

    if (tid < 64) {
        // ================= forward (wave 0) =================
        float Ecol[64];
#pragma unroll
        for (int i = 0; i < 64; ++i) Ecol[i] = __expf(trans[i * K_ + lane]);

        float e_c = ebuf[lane];
        float e00 = readlane0_f(e_c);
        float p = __expf(e_c - e00);     // e^{alpha_0} = p * e^C
        float C = e00;
        float logD0prev = 0.f;           // -log(g) of pending normalizer
        // prefetch t=1 emission transform (g=1 initially)
        float e_n = ebuf[K_ + lane];
        float en0 = readlane0_f(e_n);
        float xg = __expf(e_n - en0);    // x * g

        for (int t = 1; t < T_; ++t) {
            pbuf[lane] = p;              // single wave: DS in-order, no barrier
            float e_f = (t < T_ - 1) ? ebuf[(t + 1) * K_ + lane] : 0.f;
            // batched broadcast reads (q[16] forces all 16 ds_read_b128 first)
            float4 q[16];
#pragma unroll
            for (int i = 0; i < 16; ++i) q[i] = ((const float4*)pbuf)[i];
            float a0 = 0.f, a1 = 0.f, a2 = 0.f, a3 = 0.f;
            float a4 = 0.f, a5 = 0.f, a6 = 0.f, a7 = 0.f;
#pragma unroll
            for (int i = 0; i < 8; ++i) {
                a0 += q[2 * i].x     * Ecol[8 * i + 0];
                a1 += q[2 * i].y     * Ecol[8 * i + 1];
                a2 += q[2 * i].z     * Ecol[8 * i + 2];
                a3 += q[2 * i].w     * Ecol[8 * i + 3];
                a4 += q[2 * i + 1].x * Ecol[8 * i + 4];
                a5 += q[2 * i + 1].y * Ecol[8 * i + 5];
                a6 += q[2 * i + 1].z * Ecol[8 * i + 6];
                a7 += q[2 * i + 1].w * Ecol[8 * i + 7];
            }
            float D = ((a0 + a1) + (a2 + a3)) + ((a4 + a5) + (a6 + a7));
            float pnew = D * xg;         // the only on-chain op after the dot
            bool run = (t < seq_len);
            if (run) { p = pnew; C += en0 + logD0prev; }
            // off-chain prep for next step (one-iteration slack)
            float D0 = readlane0_f(D);
            logD0prev = __logf(D0);
            float gn = __fdividef(1.f, D0);
            en0 = readlane0_f(e_f);
            xg = __expf(e_f - en0) * gn;
            e_n = e_f;
        }
        // log_norm = C + log(sum_j p_j)
        float rs = p;
#pragma unroll
        for (int m = 32; m; m >>= 1) rs += __shfl_xor(rs, m, 64);
        float log_norm = C + __logf(rs);

        // ---------------- sequence score ----------------
        float sc = 0.f;
#pragma unroll
        for (int k = 0; k < 4; ++k) {
            int t = lane + k * 64;
            if (t < seq_len) {
                int tg = target[b * T_ + t];
                sc += ebuf[t * K_ + tg];
                if (t >= 1) sc += trans[target[b * T_ + t - 1] * K_ + tg];
            }
        }
#pragma unroll
        for (int m = 32; m; m >>= 1) sc += __shfl_xor(sc, m, 64);
        if (lane == 0) out[BT_ + b] = sc - log_norm;
    } else {
        // ================= Viterbi (wave 1) =================
        float Tcol[64];
#pragma unroll
        for (int i = 0; i < 64; ++i) Tcol[i] = trans[i * K_ + lane];
        for (int idx = lane; idx < K_ * K_; idx += 64)
            tbuf[(idx >> 6) * 65 + (idx & 63)] = trans[idx];

        float v = ebuf[lane];
        vbuf[lane] = v;
        float e_n = ebuf[K_ + lane];
        for (int t = 1; t < T_; ++t) {
            float e_f = (t < T_ - 1) ? ebuf[(t + 1) * K_ + lane] : 0.f;
            float4 q[16];
            const float4* vp = (const float4*)&vbuf[(t - 1) * K_];
#pragma unroll
            for (int i = 0; i < 16; ++i) q[i] = vp[i];
            float m0 = -3.4e38f, m1 = m0, m2 = m0, m3 = m0;
            float m4 = m0, m5 = m0, m6 = m0, m7 = m0;
#pragma unroll
            for (int i = 0; i < 8; ++i) {
                m0 = fmaxf(m0, q[2 * i].x     + Tcol[8 * i + 0]);
                m1 = fmaxf(m1, q[2 * i].y     + Tcol[8 * i + 1]);
                m2 = fmaxf(m2, q[2 * i].z     + Tcol[8 * i + 2]);
                m3 = fmaxf(m3, q[2 * i].w     + Tcol[8 * i + 3]);
                m4 = fmaxf(m4, q[2 * i + 1].x + Tcol[8 * i + 4]);
                m5 = fmaxf(m5, q[2 * i + 1].y + Tcol[8 * i + 5]);
                m6 = fmaxf(m6, q[2 * i + 1].z + Tcol[8 * i + 6]);
                m7 = fmaxf(m7, q[2 * i + 1].w + Tcol[8 * i + 7]);
            }
            float M = fmaxf(fmaxf(fmaxf(m0, m1), fmaxf(m2, m3)),
                            fmaxf(fmaxf(m4, m5), fmaxf(m6, m7)));
            float vn = M + e_n;
            if (t < seq_len) v = vn;
            vbuf[t * K_ + lane] = v;
            e_n = e_f;
        }

        // last tag: first index of max over lanes (np.argmax tie rule)
        float M = wave_max64(v);
        unsigned long long ball = __ballot(v >= M);
        int tag = (int)__builtin_ctzll(ball);

        int path[4];
#pragma unroll
        for (int k = 0; k < 4; ++k) path[k] = 0;
        if (lane == ((T_ - 1) & 63)) path[(T_ - 1) >> 6] = tag;

        float vpre = vbuf[(T_ - 2) * K_ + lane];
        for (int t = T_ - 1; t >= 1; --t) {
            float vnext = (t >= 2) ? vbuf[(t - 2) * K_ + lane] : 0.f;
            if (t < seq_len) {
                float s = vpre + tbuf[lane * 65 + tag];
                float Ms = wave_max64(s);
                unsigned long long bl = __ballot(s >= Ms);
                tag = (int)__builtin_ctzll(bl);
            }
            int pidx = t - 1;
            if (lane == (pidx & 63)) path[pidx >> 6] = tag;
            vpre = vnext;
        }
#pragma unroll
        for (int k = 0; k < 4; ++k) {
            int t = lane + k * 64;
            out[b * T_ + t] = (t < seq_len) ? (float)path[k] : 0.f;
        }
    }
}

// ---------------------------------------------------------------------------
extern "C" void kernel_launch(void* const* d_in, const int* in_sizes, int n_in,
                              void* d_out, int out_size, void* d_ws, size_t ws_size,
                              hipStream_t stream) {
    const float* hidden = (const float*)d_in[0];
    const int* masks    = (const int*)d_in[1];
    const int* target   = (const int*)d_in[2];
    const float* W      = (const float*)d_in[3];
    const float* bias   = (const float*)d_in[4];
    const float* trans  = (const float*)d_in[5];
    float* out = (float*)d_out;
    float* emis = (float*)d_ws;

    gemm_emis<<<dim3(BT_ / 128), dim3(256), 0, stream>>>(hidden, W, bias, emis);
    crf_kernel<<<dim3(B_), dim3(128), 0, stream>>>(emis, masks, target, trans, out);
}

// Round 6
// 377.865 us; speedup vs baseline: 1.0967x; 1.0255x over previous
//
#include <hip/hip_runtime.h>

#define B_ 128
#define T_ 256
#define H_ 768
#define K_ 64
#define BT_ (B_ * T_)

// ---------------------------------------------------------------------------
// DPP helpers: wave-wide max in ~6 VALU ops (row_shr/bcast ladder).
// ---------------------------------------------------------------------------
template <int CTRL>
__device__ __forceinline__ float dpp_mov_f(float x) {
    return __int_as_float(__builtin_amdgcn_update_dpp(
        __float_as_int(x), __float_as_int(x), CTRL, 0xF, 0xF, false));
}
__device__ __forceinline__ float wave_max64(float x) {
    x = fmaxf(x, dpp_mov_f<0x111>(x));  // row_shr:1
    x = fmaxf(x, dpp_mov_f<0x112>(x));  // row_shr:2
    x = fmaxf(x, dpp_mov_f<0x114>(x));  // row_shr:4
    x = fmaxf(x, dpp_mov_f<0x118>(x));  // row_shr:8
    x = fmaxf(x, dpp_mov_f<0x142>(x));  // row_bcast:15
    x = fmaxf(x, dpp_mov_f<0x143>(x));  // row_bcast:31
    return __int_as_float(__builtin_amdgcn_readlane(__float_as_int(x), 63));
}
__device__ __forceinline__ float readlane0_f(float x) {
    return __int_as_float(__builtin_amdgcn_readfirstlane(__float_as_int(x)));
}
template <int I>
__device__ __forceinline__ float readlane_f(float x) {
    return __int_as_float(__builtin_amdgcn_readlane(__float_as_int(x), I));
}

// ---------------------------------------------------------------------------
// Kernel A: emissions = hidden @ W + b  (unchanged from round 4)
// ---------------------------------------------------------------------------
#define BK_ 32
#define P_ 130
__global__ __launch_bounds__(256) void gemm_emis(const float* __restrict__ hidden,
                                                 const float* __restrict__ W,
                                                 const float* __restrict__ bias,
                                                 float* __restrict__ emis) {
    __shared__ float At[BK_ * P_];

    const int tid = threadIdx.x;
    const int lane = tid & 63;
    const int wc = __builtin_amdgcn_readfirstlane((tid >> 6) * 16);
    const int rowbase = blockIdx.x * 128;
    const int srow = tid >> 3;
    const int sh4 = tid & 7;

    float acc0[16], acc1[16];
#pragma unroll
    for (int c = 0; c < 16; ++c) { acc0[c] = bias[wc + c]; acc1[c] = acc0[c]; }

    float4 pf[4];
#pragma unroll
    for (int i = 0; i < 4; ++i)
        pf[i] = *(const float4*)&hidden[(rowbase + srow + i * 32) * H_ + sh4 * 4];

    for (int kb = 0; kb < H_ / BK_; ++kb) {
        __syncthreads();
#pragma unroll
        for (int i = 0; i < 4; ++i) {
            int row = srow + i * 32;
            At[(sh4 * 4 + 0) * P_ + row] = pf[i].x;
            At[(sh4 * 4 + 1) * P_ + row] = pf[i].y;
            At[(sh4 * 4 + 2) * P_ + row] = pf[i].z;
            At[(sh4 * 4 + 3) * P_ + row] = pf[i].w;
        }
        __syncthreads();
        if (kb + 1 < H_ / BK_) {
#pragma unroll
            for (int i = 0; i < 4; ++i)
                pf[i] = *(const float4*)&hidden[(rowbase + srow + i * 32) * H_ +
                                                (kb + 1) * BK_ + sh4 * 4];
        }
        const float* Wk = &W[(kb * BK_) * K_ + wc];
#pragma unroll 8
        for (int h = 0; h < BK_; ++h) {
            float2 a = *(const float2*)&At[h * P_ + 2 * lane];
            float4 w0 = *(const float4*)&Wk[h * K_ + 0];
            float4 w1 = *(const float4*)&Wk[h * K_ + 4];
            float4 w2 = *(const float4*)&Wk[h * K_ + 8];
            float4 w3 = *(const float4*)&Wk[h * K_ + 12];
            acc0[0]  += a.x * w0.x; acc1[0]  += a.y * w0.x;
            acc0[1]  += a.x * w0.y; acc1[1]  += a.y * w0.y;
            acc0[2]  += a.x * w0.z; acc1[2]  += a.y * w0.z;
            acc0[3]  += a.x * w0.w; acc1[3]  += a.y * w0.w;
            acc0[4]  += a.x * w1.x; acc1[4]  += a.y * w1.x;
            acc0[5]  += a.x * w1.y; acc1[5]  += a.y * w1.y;
            acc0[6]  += a.x * w1.z; acc1[6]  += a.y * w1.z;
            acc0[7]  += a.x * w1.w; acc1[7]  += a.y * w1.w;
            acc0[8]  += a.x * w2.x; acc1[8]  += a.y * w2.x;
            acc0[9]  += a.x * w2.y; acc1[9]  += a.y * w2.y;
            acc0[10] += a.x * w2.z; acc1[10] += a.y * w2.z;
            acc0[11] += a.x * w2.w; acc1[11] += a.y * w2.w;
            acc0[12] += a.x * w3.x; acc1[12] += a.y * w3.x;
            acc0[13] += a.x * w3.y; acc1[13] += a.y * w3.y;
            acc0[14] += a.x * w3.z; acc1[14] += a.y * w3.z;
            acc0[15] += a.x * w3.w; acc1[15] += a.y * w3.w;
        }
    }

    float* e0 = &emis[(size_t)(rowbase + 2 * lane) * K_ + wc];
    float* e1 = &emis[(size_t)(rowbase + 2 * lane + 1) * K_ + wc];
#pragma unroll
    for (int q = 0; q < 4; ++q) {
        *(float4*)&e0[q * 4] = make_float4(acc0[q * 4], acc0[q * 4 + 1],
                                           acc0[q * 4 + 2], acc0[q * 4 + 3]);
        *(float4*)&e1[q * 4] = make_float4(acc1[q * 4], acc1[q * 4 + 1],
                                           acc1[q * 4 + 2], acc1[q * 4 + 3]);
    }
}

// ---------------------------------------------------------------------------
// Kernel B: fused CRF. 128 blocks x 128 thr (2 waves). The all-to-all
// broadcast of p / v is done with v_readlane (VALU pipe, zero DS ops on the
// serial chain) instead of an LDS round-trip — rounds 4/5 showed the
// scheduler serializes per-step DS reads at ~full latency (~1500 cyc/step).
// ---------------------------------------------------------------------------
__global__ __launch_bounds__(128, 1) void crf_kernel(const float* __restrict__ emis,
                                                     const int* __restrict__ masks,
                                                     const int* __restrict__ target,
                                                     const float* __restrict__ trans,
                                                     float* __restrict__ out) {
    __shared__ __align__(16) float ebuf[T_ * K_];   // 64 KB emissions for batch b
    __shared__ __align__(16) float vbuf[T_ * K_];   // 64 KB viterbi v-history
    __shared__ float tbuf[K_ * 65];                 // padded trans rows (backtrack)

    const int tid = threadIdx.x;
    const int lane = tid & 63;
    const int b = blockIdx.x;
    const float* eb = emis + (size_t)b * (T_ * K_);

    // stage emissions: 4096 float4s over 128 threads
    {
        const float4* src = (const float4*)eb;
        float4* dst = (float4*)ebuf;
#pragma unroll
        for (int k = 0; k < 32; ++k) dst[tid + k * 128] = src[tid + k * 128];
    }
    int sl = 0;
#pragma unroll
    for (int k = 0; k < 4; ++k) sl += masks[b * T_ + lane + k * 64];
#pragma unroll
    for (int m = 32; m; m >>= 1) sl += __shfl_xor(sl, m, 64);
    const int seq_len = sl;
    __syncthreads();

    if (tid < 64) {
        // ================= forward (wave 0), delayed normalization ==========
        float Ecol[64];
#pragma unroll
        for (int i = 0; i < 64; ++i) Ecol[i] = __expf(trans[i * K_ + lane]);

        float e_c = ebuf[lane];
        float e00 = readlane0_f(e_c);
        float p = __expf(e_c - e00);     // e^{alpha_0} = p * e^C
        float C = e00;
        float logD0prev = 0.f;
        float e_n = ebuf[K_ + lane];
        float en0 = readlane0_f(e_n);
        float xg = __expf(e_n - en0);    // x * g

        for (int t = 1; t < T_; ++t) {
            float e_f = (t < T_ - 1) ? ebuf[(t + 1) * K_ + lane] : 0.f;
            float a0 = 0.f, a1 = 0.f, a2 = 0.f, a3 = 0.f;
            float a4 = 0.f, a5 = 0.f, a6 = 0.f, a7 = 0.f;
            // all-to-all via readlane: pure VALU, no DS on the chain
#define FWD8(base)                                                     \
            a0 = fmaf(readlane_f<base + 0>(p), Ecol[base + 0], a0);    \
            a1 = fmaf(readlane_f<base + 1>(p), Ecol[base + 1], a1);    \
            a2 = fmaf(readlane_f<base + 2>(p), Ecol[base + 2], a2);    \
            a3 = fmaf(readlane_f<base + 3>(p), Ecol[base + 3], a3);    \
            a4 = fmaf(readlane_f<base + 4>(p), Ecol[base + 4], a4);    \
            a5 = fmaf(readlane_f<base + 5>(p), Ecol[base + 5], a5);    \
            a6 = fmaf(readlane_f<base + 6>(p), Ecol[base + 6], a6);    \
            a7 = fmaf(readlane_f<base + 7>(p), Ecol[base + 7], a7);
            FWD8(0) FWD8(8) FWD8(16) FWD8(24) FWD8(32) FWD8(40) FWD8(48) FWD8(56)
#undef FWD8
            float D = ((a0 + a1) + (a2 + a3)) + ((a4 + a5) + (a6 + a7));
            float pnew = D * xg;         // only on-chain op after the dot
            if (t < seq_len) { p = pnew; C += en0 + logD0prev; }
            // off-chain prep for next step
            float D0 = readlane0_f(D);
            logD0prev = __logf(D0);
            float gn = __fdividef(1.f, D0);
            en0 = readlane0_f(e_f);
            xg = __expf(e_f - en0) * gn;
            e_n = e_f;
        }
        float rs = p;
#pragma unroll
        for (int m = 32; m; m >>= 1) rs += __shfl_xor(rs, m, 64);
        float log_norm = C + __logf(rs);

        // ---------------- sequence score ----------------
        float sc = 0.f;
#pragma unroll
        for (int k = 0; k < 4; ++k) {
            int t = lane + k * 64;
            if (t < seq_len) {
                int tg = target[b * T_ + t];
                sc += ebuf[t * K_ + tg];
                if (t >= 1) sc += trans[target[b * T_ + t - 1] * K_ + tg];
            }
        }
#pragma unroll
        for (int m = 32; m; m >>= 1) sc += __shfl_xor(sc, m, 64);
        if (lane == 0) out[BT_ + b] = sc - log_norm;
    } else {
        // ================= Viterbi (wave 1): readlane max-plus ==============
        float Tcol[64];
#pragma unroll
        for (int i = 0; i < 64; ++i) Tcol[i] = trans[i * K_ + lane];
        for (int idx = lane; idx < K_ * K_; idx += 64)
            tbuf[(idx >> 6) * 65 + (idx & 63)] = trans[idx];

        float v = ebuf[lane];
        vbuf[lane] = v;
        float e_n = ebuf[K_ + lane];
        for (int t = 1; t < T_; ++t) {
            float e_f = (t < T_ - 1) ? ebuf[(t + 1) * K_ + lane] : 0.f;
            float m0 = -3.4e38f, m1 = m0, m2 = m0, m3 = m0;
            float m4 = m0, m5 = m0, m6 = m0, m7 = m0;
#define VIT8(base)                                                        \
            m0 = fmaxf(m0, readlane_f<base + 0>(v) + Tcol[base + 0]);     \
            m1 = fmaxf(m1, readlane_f<base + 1>(v) + Tcol[base + 1]);     \
            m2 = fmaxf(m2, readlane_f<base + 2>(v) + Tcol[base + 2]);     \
            m3 = fmaxf(m3, readlane_f<base + 3>(v) + Tcol[base + 3]);     \
            m4 = fmaxf(m4, readlane_f<base + 4>(v) + Tcol[base + 4]);     \
            m5 = fmaxf(m5, readlane_f<base + 5>(v) + Tcol[base + 5]);     \
            m6 = fmaxf(m6, readlane_f<base + 6>(v) + Tcol[base + 6]);     \
            m7 = fmaxf(m7, readlane_f<base + 7>(v) + Tcol[base + 7]);
            VIT8(0) VIT8(8) VIT8(16) VIT8(24) VIT8(32) VIT8(40) VIT8(48) VIT8(56)
#undef VIT8
            float M = fmaxf(fmaxf(fmaxf(m0, m1), fmaxf(m2, m3)),
                            fmaxf(fmaxf(m4, m5), fmaxf(m6, m7)));
            float vn = M + e_n;
            if (t < seq_len) v = vn;
            vbuf[t * K_ + lane] = v;   // off-chain ds_write (history)
            e_n = e_f;
        }

        // last tag: first index of max over lanes (np.argmax tie rule)
        float M = wave_max64(v);
        unsigned long long ball = __ballot(v >= M);
        int tag = (int)__builtin_ctzll(ball);

        int path[4];
#pragma unroll
        for (int k = 0; k < 4; ++k) path[k] = 0;
        if (lane == ((T_ - 1) & 63)) path[(T_ - 1) >> 6] = tag;

        float vpre = vbuf[(T_ - 2) * K_ + lane];
        for (int t = T_ - 1; t >= 1; --t) {
            float vnext = (t >= 2) ? vbuf[(t - 2) * K_ + lane] : 0.f;
            if (t < seq_len) {
                float s = vpre + tbuf[lane * 65 + tag];
                float Ms = wave_max64(s);
                unsigned long long bl = __ballot(s >= Ms);
                tag = (int)__builtin_ctzll(bl);
            }
            int pidx = t - 1;
            if (lane == (pidx & 63)) path[pidx >> 6] = tag;
            vpre = vnext;
        }
#pragma unroll
        for (int k = 0; k < 4; ++k) {
            int t = lane + k * 64;
            out[b * T_ + t] = (t < seq_len) ? (float)path[k] : 0.f;
        }
    }
}

// ---------------------------------------------------------------------------
extern "C" void kernel_launch(void* const* d_in, const int* in_sizes, int n_in,
                              void* d_out, int out_size, void* d_ws, size_t ws_size,
                              hipStream_t stream) {
    const float* hidden = (const float*)d_in[0];
    const int* masks    = (const int*)d_in[1];
    const int* target   = (const int*)d_in[2];
    const float* W      = (const float*)d_in[3];
    const float* bias   = (const float*)d_in[4];
    const float* trans  = (const float*)d_in[5];
    float* out = (float*)d_out;
    float* emis = (float*)d_ws;

    gemm_emis<<<dim3(BT_ / 128), dim3(256), 0, stream>>>(hidden, W, bias, emis);
    crf_kernel<<<dim3(B_), dim3(128), 0, stream>>>(emis, masks, target, trans, out);
}